// Round 10
// baseline (93.025 us; speedup 1.0000x reference)
//
#include <hip/hip_runtime.h>
#include <hip/hip_bf16.h>

#define B_    8
#define S_    2048
#define D_    2048
#define DS_   64
#define NUSED 1536
#define TOK   16384  // B_*S_

typedef __attribute__((ext_vector_type(8))) short bf16x8;
typedef __attribute__((ext_vector_type(4))) float f32x4;

// ws layout (float offsets)
static constexpr int WS_ETF  = 0;          // etfrag: 196608 shorts (98304 f)
static constexpr int WS_HT   = 98304;      // htp[2][64][16384] f32
static constexpr int WS_PART = 2195456;    // part[1024][1536]
static constexpr int WS_WF   = 3768320;    // wfrag: 262144 shorts

typedef __attribute__((address_space(1))) const void g_void;
typedef __attribute__((address_space(3))) void l_void;

__device__ inline short bf_hi(float f, float& rhi) {
    __hip_bfloat16 h = __float2bfloat16(f);
    rhi = __bfloat162float(h);
    return __builtin_bit_cast(short, h);
}
__device__ inline short bf_of(float f) {
    __hip_bfloat16 h = __float2bfloat16(f);
    return __builtin_bit_cast(short, h);
}
__device__ inline int sliceOfTile(int tile) {
    return tile < 32 ? 0 : tile < 64 ? 1 : tile < 80 ? 2 : 3;
}

// ---------------- K_pre: fused embpack (blocks 0..47) + wsplit (48..111) ---
__launch_bounds__(256)
__global__ void k_pre(const float* __restrict__ emb, const float* __restrict__ W,
                      short* __restrict__ etfrag, short* __restrict__ wfrag) {
    __shared__ float red[2][16][8];
    __shared__ float rn[2][16];
    const int tid = threadIdx.x;
    if (blockIdx.x < 48) {
        const int tl = tid >> 7, tid2 = tid & 127;
        const int kh = tid2 >> 6, lane = tid2 & 63;
        const int tile = blockIdx.x * 2 + tl;
        const int nl = lane & 15;
        const int n = tile * 16 + nl;
        const int kb = kh * 32 + (lane >> 4) * 8;
        const float* ep = emb + n * DS_ + kb;
        float4 a = *reinterpret_cast<const float4*>(ep);
        float4 b = *reinterpret_cast<const float4*>(ep + 4);
        float f[8] = {a.x, a.y, a.z, a.w, b.x, b.y, b.z, b.w};
        float ss = 0.f;
#pragma unroll
        for (int j = 0; j < 8; ++j) ss += f[j] * f[j];
        red[tl][nl][kh * 4 + (lane >> 4)] = ss;
        __syncthreads();
        if (tid2 < 16) {
            float s = 0.f;
#pragma unroll
            for (int j = 0; j < 8; ++j) s += red[tl][tid2][j];
            rn[tl][tid2] = 1.0f / sqrtf(s);
        }
        __syncthreads();
        const float r0 = rn[tl][nl];
        bf16x8 hi, lo;
#pragma unroll
        for (int j = 0; j < 8; ++j) {
            float v = f[j] * r0, r;
            hi[j] = bf_hi(v, r);
            lo[j] = bf_of(v - r);
        }
        short* dst = etfrag + (size_t)((tile * 2 + kh) * 64 + lane) * 16;
        *reinterpret_cast<bf16x8*>(dst)     = hi;
        *reinterpret_cast<bf16x8*>(dst + 8) = lo;
    } else {
        const int kstep = blockIdx.x - 48;
        const int msub = tid >> 6, lane = tid & 63;
        const int m = msub * 16 + (lane & 15);
        const float* wp = W + m * D_ + kstep * 32 + (lane >> 4) * 8;
        float4 a = *reinterpret_cast<const float4*>(wp);
        float4 b = *reinterpret_cast<const float4*>(wp + 4);
        float f[8] = {a.x, a.y, a.z, a.w, b.x, b.y, b.z, b.w};
        bf16x8 hi, lo;
#pragma unroll
        for (int j = 0; j < 8; ++j) {
            float r;
            hi[j] = bf_hi(f[j], r);
            lo[j] = bf_of(f[j] - r);
        }
        short* base = wfrag + (size_t)(kstep * 4 + msub) * 1024;
        *reinterpret_cast<bf16x8*>(base + lane * 8)       = hi;
        *reinterpret_cast<bf16x8*>(base + 512 + lane * 8) = lo;
    }
}

// ---------------- K2: h^T = W @ x^T, split-bf16 MFMA, LDS W, 2-ks groups ---
#define MFMA16(A, Bv, C) __builtin_amdgcn_mfma_f32_16x16x32_bf16(A, Bv, C, 0, 0, 0)

__launch_bounds__(256, 2)
__global__ void k_gemm1(const float* __restrict__ x, const short* __restrict__ wfrag,
                        float* __restrict__ htp) {
    __shared__ short wlds[2][2][4096];   // [buf][ks-in-group][4096 shorts] = 32 KB

    const int tid   = threadIdx.x;
    const int split = blockIdx.x & 1;
    const int tb    = (blockIdx.x >> 1) * 64;
    const int wave  = tid >> 6, lane = tid & 63;
    const int tok   = tb + wave * 16 + (lane & 15);

    const float* xp   = x + (size_t)tok * D_ + split * 1024 + (lane >> 4) * 8;
    const short* wsrc = wfrag + (size_t)(split * 32) * 4096;

    f32x4 acc0 = {0.f, 0.f, 0.f, 0.f};
    f32x4 acc1 = acc0, acc2 = acc0, acc3 = acc0;

#define STAGE(g, buf)                                                                        \
    {                                                                                        \
        const short* s0 = wsrc + (size_t)(2 * (g)) * 4096;                                   \
        __builtin_amdgcn_global_load_lds((g_void*)(s0 + tid * 8),                            \
                                         (l_void*)(&wlds[buf][0][tid * 8]), 16, 0, 0);       \
        __builtin_amdgcn_global_load_lds((g_void*)(s0 + 2048 + tid * 8),                     \
                                         (l_void*)(&wlds[buf][0][2048 + tid * 8]), 16, 0, 0);\
        __builtin_amdgcn_global_load_lds((g_void*)(s0 + 4096 + tid * 8),                     \
                                         (l_void*)(&wlds[buf][1][tid * 8]), 16, 0, 0);       \
        __builtin_amdgcn_global_load_lds((g_void*)(s0 + 6144 + tid * 8),                     \
                                         (l_void*)(&wlds[buf][1][2048 + tid * 8]), 16, 0, 0);\
    }

    STAGE(0, 0);
    float4 xc0 = *reinterpret_cast<const float4*>(xp);
    float4 xc1 = *reinterpret_cast<const float4*>(xp + 4);
    float4 xc2 = *reinterpret_cast<const float4*>(xp + 32);
    float4 xc3 = *reinterpret_cast<const float4*>(xp + 36);

#pragma unroll 2
    for (int g = 0; g < 16; ++g) {
        __syncthreads();   // group g's W staged + group g's x drained
        const int buf = g & 1;
        float4 xn0, xn1, xn2, xn3;
        if (g < 15) {      // issue group g+1: W -> LDS(buf^1), x -> regs
            STAGE(g + 1, buf ^ 1);
            const float* nxp = xp + (size_t)(g + 1) * 64;
            xn0 = *reinterpret_cast<const float4*>(nxp);
            xn1 = *reinterpret_cast<const float4*>(nxp + 4);
            xn2 = *reinterpret_cast<const float4*>(nxp + 32);
            xn3 = *reinterpret_cast<const float4*>(nxp + 36);
        }
#pragma unroll
        for (int kk = 0; kk < 2; ++kk) {
            const float4 va = kk ? xc2 : xc0;
            const float4 vb = kk ? xc3 : xc1;
            float xf[8] = {va.x, va.y, va.z, va.w, vb.x, vb.y, vb.z, vb.w};
            bf16x8 bh, bl;
#pragma unroll
            for (int j = 0; j < 8; ++j) {
                float r;
                bh[j] = bf_hi(xf[j], r);
                bl[j] = bf_of(xf[j] - r);
            }
            const short* wl = &wlds[buf][kk][0];
            bf16x8 ah0 = *reinterpret_cast<const bf16x8*>(wl +    0 + lane * 8);
            bf16x8 al0 = *reinterpret_cast<const bf16x8*>(wl +  512 + lane * 8);
            bf16x8 ah1 = *reinterpret_cast<const bf16x8*>(wl + 1024 + lane * 8);
            bf16x8 al1 = *reinterpret_cast<const bf16x8*>(wl + 1536 + lane * 8);
            bf16x8 ah2 = *reinterpret_cast<const bf16x8*>(wl + 2048 + lane * 8);
            bf16x8 al2 = *reinterpret_cast<const bf16x8*>(wl + 2560 + lane * 8);
            bf16x8 ah3 = *reinterpret_cast<const bf16x8*>(wl + 3072 + lane * 8);
            bf16x8 al3 = *reinterpret_cast<const bf16x8*>(wl + 3584 + lane * 8);

            acc0 = MFMA16(ah0, bh, acc0);
            acc1 = MFMA16(ah1, bh, acc1);
            acc2 = MFMA16(ah2, bh, acc2);
            acc3 = MFMA16(ah3, bh, acc3);
            acc0 = MFMA16(al0, bh, acc0);
            acc1 = MFMA16(al1, bh, acc1);
            acc2 = MFMA16(al2, bh, acc2);
            acc3 = MFMA16(al3, bh, acc3);
            acc0 = MFMA16(ah0, bl, acc0);
            acc1 = MFMA16(ah1, bl, acc1);
            acc2 = MFMA16(ah2, bl, acc2);
            acc3 = MFMA16(ah3, bl, acc3);
        }
        if (g < 15) { xc0 = xn0; xc1 = xn1; xc2 = xn2; xc3 = xn3; }
    }

    const int row0 = split * 64 + (lane >> 4) * 4;
    const int col  = tb + wave * 16 + (lane & 15);
#pragma unroll
    for (int r = 0; r < 4; ++r) {
        htp[(size_t)(row0 +  0 + r) * TOK + col] = acc0[r];
        htp[(size_t)(row0 + 16 + r) * TOK + col] = acc1[r];
        htp[(size_t)(row0 + 32 + r) * TOK + col] = acc2[r];
        htp[(size_t)(row0 + 48 + r) * TOK + col] = acc3[r];
    }
}

// ---------------- K3: MFMA routing, 32 tokens/block, 16 waves x 6 tiles ----
__launch_bounds__(1024)
__global__ void k_route2(const float* __restrict__ htp, const float* __restrict__ bias,
                         const short* __restrict__ etfrag, const float* __restrict__ imp,
                         float* __restrict__ part) {
    __shared__ float h_lds[64][32];
    __shared__ float zw[2][16][2][16];
    __shared__ float coef[2][4][16];
    __shared__ float impb[32];

    const int tid = threadIdx.x;
    const int w = tid >> 6, lane = tid & 63;
    const int tt2 = blockIdx.x;            // 32-token group (0..511)
    const int tk = lane & 15, g = lane >> 4;

    // prologue: h = htp[split0] + htp[split1] + bias for 32 tokens
    if (tid < 512) {
        const int k = tid >> 3, c8 = tid & 7;
        const float4* hp4 = reinterpret_cast<const float4*>(htp);
        const int col = tt2 * 8 + c8;
        float4 a = hp4[(size_t)k * 4096 + col];
        float4 b = hp4[(size_t)(k + 64) * 4096 + col];
        float bk = bias[k];
        float4 s;
        s.x = a.x + b.x + bk;
        s.y = a.y + b.y + bk;
        s.z = a.z + b.z + bk;
        s.w = a.w + b.w + bk;
        *reinterpret_cast<float4*>(&h_lds[k][c8 * 4]) = s;
    }
    if (tid < 32) impb[tid] = imp[tt2 * 32 + tid];
    __syncthreads();

    // B-fragments for the two token-tiles (value-identical to round 7)
    bf16x8 bh0A, bl0A, bh1A, bl1A, bh0B, bl0B, bh1B, bl1B;
#pragma unroll
    for (int j = 0; j < 8; ++j) {
        float r, v;
        v = h_lds[g * 8 + j][tk];           bh0A[j] = bf_hi(v, r); bl0A[j] = bf_of(v - r);
        v = h_lds[32 + g * 8 + j][tk];      bh1A[j] = bf_hi(v, r); bl1A[j] = bf_of(v - r);
        v = h_lds[g * 8 + j][16 + tk];      bh0B[j] = bf_hi(v, r); bl0B[j] = bf_of(v - r);
        v = h_lds[32 + g * 8 + j][16 + tk]; bh1B[j] = bf_hi(v, r); bl1B[j] = bf_of(v - r);
    }

    const int t0 = w * 6;                 // 16 waves x 6 tiles = 96
    const int sA = sliceOfTile(t0);
    const int sB = sliceOfTile(t0 + 5);
    float zA0 = 0.f, zA1 = 0.f, zB0 = 0.f, zB1 = 0.f;
    float pA[6][4], pB[6][4];   // fp32 p, statically indexed (full unroll)

    const short* ep = etfrag + (size_t)t0 * 2048 + lane * 16;
#pragma unroll
    for (int ti = 0; ti < 6; ++ti) {
        const short* cp = ep + (size_t)ti * 2048;
        bf16x8 ah0 = *reinterpret_cast<const bf16x8*>(cp);
        bf16x8 al0 = *reinterpret_cast<const bf16x8*>(cp + 8);
        bf16x8 ah1 = *reinterpret_cast<const bf16x8*>(cp + 1024);
        bf16x8 al1 = *reinterpret_cast<const bf16x8*>(cp + 1032);
        f32x4 a0 = {0.f, 0.f, 0.f, 0.f};
        f32x4 a1 = a0, b0 = a0, b1 = a0;
        a0 = MFMA16(ah0, bh0A, a0);  b0 = MFMA16(ah0, bh0B, b0);
        a1 = MFMA16(ah1, bh1A, a1);  b1 = MFMA16(ah1, bh1B, b1);
        a0 = MFMA16(al0, bh0A, a0);  b0 = MFMA16(al0, bh0B, b0);
        a1 = MFMA16(al1, bh1A, a1);  b1 = MFMA16(al1, bh1B, b1);
        a0 = MFMA16(ah0, bl0A, a0);  b0 = MFMA16(ah0, bl0B, b0);
        a1 = MFMA16(ah1, bl1A, a1);  b1 = MFMA16(ah1, bl1B, b1);

        const float pa0 = __expf(a0[0] + a1[0]);
        const float pa1 = __expf(a0[1] + a1[1]);
        const float pa2 = __expf(a0[2] + a1[2]);
        const float pa3 = __expf(a0[3] + a1[3]);
        pA[ti][0] = pa0; pA[ti][1] = pa1; pA[ti][2] = pa2; pA[ti][3] = pa3;
        const float zsA = (pa0 + pa1) + (pa2 + pa3);
        const float pb0 = __expf(b0[0] + b1[0]);
        const float pb1 = __expf(b0[1] + b1[1]);
        const float pb2 = __expf(b0[2] + b1[2]);
        const float pb3 = __expf(b0[3] + b1[3]);
        pB[ti][0] = pb0; pB[ti][1] = pb1; pB[ti][2] = pb2; pB[ti][3] = pb3;
        const float zsB = (pb0 + pb1) + (pb2 + pb3);
        if (sliceOfTile(t0 + ti) == sA) { zA0 += zsA; zB0 += zsB; }
        else                            { zA1 += zsA; zB1 += zsB; }
    }

    // z: reduce across the 4 row-groups (lanes differing in bits 4,5)
    zA0 += __shfl_xor(zA0, 16); zA0 += __shfl_xor(zA0, 32);
    zA1 += __shfl_xor(zA1, 16); zA1 += __shfl_xor(zA1, 32);
    zB0 += __shfl_xor(zB0, 16); zB0 += __shfl_xor(zB0, 32);
    zB1 += __shfl_xor(zB1, 16); zB1 += __shfl_xor(zB1, 32);
    if (lane < 16) {
        zw[0][w][0][lane] = zA0; zw[0][w][1][lane] = zA1;
        zw[1][w][0][lane] = zB0; zw[1][w][1][lane] = zB1;
    }
    __syncthreads();

    if (tid < 128) {
        const int tl = tid >> 6, s = (tid >> 4) & 3, k2 = tid & 15;
        float z = 0.f;
#pragma unroll
        for (int w2 = 0; w2 < 16; ++w2) {
            const int a = sliceOfTile(w2 * 6);
            const int b = sliceOfTile(w2 * 6 + 5);
            if (a == s) z += zw[tl][w2][0][k2];
            if (b == s && b != a) z += zw[tl][w2][1][k2];
        }
        coef[tl][s][k2] = impb[tl * 16 + k2] / z;
    }
    __syncthreads();

    // pass 2: dense[n] = sum_t coef[t] * p[t,n]; tokens live across tk lanes
    const float cAA = coef[0][sA][tk], cAB = coef[0][sB][tk];
    const float cBA = coef[1][sA][tk], cBB = coef[1][sB][tk];
    float* poutA = part + (size_t)(tt2 * 2) * NUSED;
    float* poutB = poutA + NUSED;
#pragma unroll
    for (int ti = 0; ti < 6; ++ti) {
        const bool inA = (sliceOfTile(t0 + ti) == sA);
        {
            const float c = inA ? cAA : cAB;
            float v0 = pA[ti][0] * c, v1 = pA[ti][1] * c, v2 = pA[ti][2] * c, v3 = pA[ti][3] * c;
#pragma unroll
            for (int st = 1; st < 16; st <<= 1) {
                v0 += __shfl_xor(v0, st);
                v1 += __shfl_xor(v1, st);
                v2 += __shfl_xor(v2, st);
                v3 += __shfl_xor(v3, st);
            }
            if (tk == 0)
                *reinterpret_cast<float4*>(&poutA[(t0 + ti) * 16 + g * 4]) =
                    make_float4(v0, v1, v2, v3);
        }
        {
            const float c = inA ? cBA : cBB;
            float v0 = pB[ti][0] * c, v1 = pB[ti][1] * c, v2 = pB[ti][2] * c, v3 = pB[ti][3] * c;
#pragma unroll
            for (int st = 1; st < 16; st <<= 1) {
                v0 += __shfl_xor(v0, st);
                v1 += __shfl_xor(v1, st);
                v2 += __shfl_xor(v2, st);
                v3 += __shfl_xor(v3, st);
            }
            if (tk == 0)
                *reinterpret_cast<float4*>(&poutB[(t0 + ti) * 16 + g * 4]) =
                    make_float4(v0, v1, v2, v3);
        }
    }
}

// ---------------- K4: merged reduce (128 rows) + top-k + output, 1 block/batch
__launch_bounds__(1024)
__global__ void kAB(const float* __restrict__ part, float* __restrict__ out) {
    __shared__ float dens[NUSED];
    __shared__ float s_v[4][8];
    __shared__ int   s_n[4][8];
    const int tid = threadIdx.x;
    const int b = blockIdx.x;
    const float* pb = part + (size_t)(b * 128) * NUSED;

#pragma unroll
    for (int i = 0; i < 2; ++i) {
        int n = tid + 1024 * i;
        if (n < NUSED) {
            float s = 0.f;
#pragma unroll 8
            for (int r = 0; r < 128; ++r) s += pb[(size_t)r * NUSED + n];
            dens[n] = s;
        }
    }
    for (int i = tid; i < 1792; i += 1024) out[b * 1792 + i] = 0.f;
    __syncthreads();

    const int w = tid >> 6, lane = tid & 63;
    if (w < 4) {
        const int soffs[4] = {0, 512, 1024, 1280};
        const int ssz[4]   = {512, 512, 256, 256};
        const int kks[4]   = {8, 8, 4, 6};
        const int ooffs[4] = {0, 512, 1024, 1536};
        const int Sn = ssz[w], soff = soffs[w], kk = kks[w];
        const int nslots = Sn >> 6;

        float v[8];
#pragma unroll
        for (int i = 0; i < 8; ++i)
            v[i] = (i < nslots) ? dens[soff + lane + 64 * i] : -1e30f;

        unsigned rm = 0;
        float ssum = 0.f;
        for (int it = 0; it < kk; ++it) {
            float bv = -1e30f;
            int bn = 0x7fffffff;
#pragma unroll
            for (int i = 0; i < 8; ++i) {
                bool valid = (i < nslots) && !((rm >> i) & 1u);
                if (valid && v[i] > bv) { bv = v[i]; bn = lane + 64 * i; }
            }
#pragma unroll
            for (int off = 32; off; off >>= 1) {
                float ov = __shfl_xor(bv, off);
                int   on = __shfl_xor(bn, off);
                if (ov > bv || (ov == bv && on < bn)) { bv = ov; bn = on; }
            }
            ssum += bv;
            if ((bn & 63) == lane) rm |= 1u << (bn >> 6);
            if (lane == 0) { s_v[w][it] = bv; s_n[w][it] = bn; }
        }
        const float inv = 1.f / (ssum + 1e-8f);
        if (lane < kk) {
            int n = s_n[w][lane];
            float val = s_v[w][lane] * inv;
            out[b * 1792 + ooffs[w] + n] = val;
            if (w == 2) out[b * 1792 + 1280 + n] = val;  // rk = rq
        }
    }
}

extern "C" void kernel_launch(void* const* d_in, const int* in_sizes, int n_in,
                              void* d_out, int out_size, void* d_ws, size_t ws_size,
                              hipStream_t stream) {
    const float* x    = (const float*)d_in[0];
    const float* imp  = (const float*)d_in[1];
    const float* W    = (const float*)d_in[2];
    const float* bias = (const float*)d_in[3];
    const float* emb  = (const float*)d_in[4];
    float* out = (float*)d_out;
    float* ws  = (float*)d_ws;

    short* etfrag = (short*)(ws + WS_ETF);
    float* htp    = ws + WS_HT;
    float* part   = ws + WS_PART;
    short* wfrag  = (short*)(ws + WS_WF);

    k_pre<<<112, 256, 0, stream>>>(emb, W, etfrag, wfrag);
    k_gemm1<<<512, 256, 0, stream>>>(x, wfrag, htp);
    k_route2<<<512, 1024, 0, stream>>>(htp, bias, etfrag, imp, part);
    kAB<<<B_, 1024, 0, stream>>>(part, out);
}

// Round 11
// 78.291 us; speedup vs baseline: 1.1882x; 1.1882x over previous
//
#include <hip/hip_runtime.h>
#include <hip/hip_bf16.h>

#define B_    8
#define S_    2048
#define D_    2048
#define DS_   64
#define NUSED 1536
#define TOK   16384  // B_*S_

typedef __attribute__((ext_vector_type(8))) short bf16x8;
typedef __attribute__((ext_vector_type(4))) float f32x4;

// ws layout (float offsets)
static constexpr int WS_ETF  = 0;          // etfrag: 196608 shorts (98304 f)
static constexpr int WS_HT   = 98304;      // htp[2][64][16384] f32
static constexpr int WS_PART = 2195456;    // part[1024][1536]
static constexpr int WS_PART2= 3768320;    // part2[64][1536]
static constexpr int WS_WF   = 3866624;    // wfrag: 262144 shorts

typedef __attribute__((address_space(1))) const void g_void;
typedef __attribute__((address_space(3))) void l_void;

__device__ inline short bf_hi(float f, float& rhi) {
    __hip_bfloat16 h = __float2bfloat16(f);
    rhi = __bfloat162float(h);
    return __builtin_bit_cast(short, h);
}
__device__ inline short bf_of(float f) {
    __hip_bfloat16 h = __float2bfloat16(f);
    return __builtin_bit_cast(short, h);
}
__device__ inline int sliceOfTile(int tile) {
    return tile < 32 ? 0 : tile < 64 ? 1 : tile < 80 ? 2 : 3;
}

// ---------------- K_pre: fused embpack (blocks 0..47) + wsplit (48..111) ---
__launch_bounds__(256)
__global__ void k_pre(const float* __restrict__ emb, const float* __restrict__ W,
                      short* __restrict__ etfrag, short* __restrict__ wfrag) {
    __shared__ float red[2][16][8];
    __shared__ float rn[2][16];
    const int tid = threadIdx.x;
    if (blockIdx.x < 48) {
        const int tl = tid >> 7, tid2 = tid & 127;
        const int kh = tid2 >> 6, lane = tid2 & 63;
        const int tile = blockIdx.x * 2 + tl;
        const int nl = lane & 15;
        const int n = tile * 16 + nl;
        const int kb = kh * 32 + (lane >> 4) * 8;
        const float* ep = emb + n * DS_ + kb;
        float4 a = *reinterpret_cast<const float4*>(ep);
        float4 b = *reinterpret_cast<const float4*>(ep + 4);
        float f[8] = {a.x, a.y, a.z, a.w, b.x, b.y, b.z, b.w};
        float ss = 0.f;
#pragma unroll
        for (int j = 0; j < 8; ++j) ss += f[j] * f[j];
        red[tl][nl][kh * 4 + (lane >> 4)] = ss;
        __syncthreads();
        if (tid2 < 16) {
            float s = 0.f;
#pragma unroll
            for (int j = 0; j < 8; ++j) s += red[tl][tid2][j];
            rn[tl][tid2] = 1.0f / sqrtf(s);
        }
        __syncthreads();
        const float r0 = rn[tl][nl];
        bf16x8 hi, lo;
#pragma unroll
        for (int j = 0; j < 8; ++j) {
            float v = f[j] * r0, r;
            hi[j] = bf_hi(v, r);
            lo[j] = bf_of(v - r);
        }
        short* dst = etfrag + (size_t)((tile * 2 + kh) * 64 + lane) * 16;
        *reinterpret_cast<bf16x8*>(dst)     = hi;
        *reinterpret_cast<bf16x8*>(dst + 8) = lo;
    } else {
        const int kstep = blockIdx.x - 48;
        const int msub = tid >> 6, lane = tid & 63;
        const int m = msub * 16 + (lane & 15);
        const float* wp = W + m * D_ + kstep * 32 + (lane >> 4) * 8;
        float4 a = *reinterpret_cast<const float4*>(wp);
        float4 b = *reinterpret_cast<const float4*>(wp + 4);
        float f[8] = {a.x, a.y, a.z, a.w, b.x, b.y, b.z, b.w};
        bf16x8 hi, lo;
#pragma unroll
        for (int j = 0; j < 8; ++j) {
            float r;
            hi[j] = bf_hi(f[j], r);
            lo[j] = bf_of(f[j] - r);
        }
        short* base = wfrag + (size_t)(kstep * 4 + msub) * 1024;
        *reinterpret_cast<bf16x8*>(base + lane * 8)       = hi;
        *reinterpret_cast<bf16x8*>(base + 512 + lane * 8) = lo;
    }
}

// ---------------- K2: h^T = W @ x^T, split-bf16 MFMA, LDS W, 4-ks groups ---
#define MFMA16(A, Bv, C) __builtin_amdgcn_mfma_f32_16x16x32_bf16(A, Bv, C, 0, 0, 0)

__launch_bounds__(256, 2)
__global__ void k_gemm1(const float* __restrict__ x, const short* __restrict__ wfrag,
                        float* __restrict__ htp) {
    __shared__ short wlds[2][4][4096];   // 64 KB: [buf][ks-in-group][4 msub * (512hi+512lo)]

    const int tid   = threadIdx.x;
    const int split = blockIdx.x & 1;
    const int tb    = (blockIdx.x >> 1) * 64;
    const int wave  = tid >> 6, lane = tid & 63;
    const int tok   = tb + wave * 16 + (lane & 15);

    const float* xp   = x + (size_t)tok * D_ + split * 1024 + (lane >> 4) * 8;
    const short* wsrc = wfrag + (size_t)(split * 32) * 4096;

    f32x4 acc0 = {0.f, 0.f, 0.f, 0.f};
    f32x4 acc1 = acc0, acc2 = acc0, acc3 = acc0;

#define STAGE4(gg, buf)                                                                      \
    {                                                                                        \
        _Pragma("unroll")                                                                    \
        for (int s = 0; s < 4; ++s) {                                                        \
            const short* s0 = wsrc + (size_t)(4 * (gg) + s) * 4096;                          \
            __builtin_amdgcn_global_load_lds((g_void*)(s0 + tid * 8),                        \
                                             (l_void*)(&wlds[buf][s][tid * 8]), 16, 0, 0);   \
            __builtin_amdgcn_global_load_lds((g_void*)(s0 + 2048 + tid * 8),                 \
                                             (l_void*)(&wlds[buf][s][2048 + tid * 8]), 16, 0, 0); \
        }                                                                                    \
    }

    STAGE4(0, 0);
    float4 xc[4], xn[4];
#pragma unroll
    for (int i = 0; i < 4; ++i)
        xc[i] = *reinterpret_cast<const float4*>(xp + (i >> 1) * 32 + (i & 1) * 4);

    for (int g = 0; g < 8; ++g) {
        __syncthreads();   // W(group g) staged; x/W prefetches drained
        const int buf = g & 1;
        if (g < 7) STAGE4(g + 1, buf ^ 1);

#pragma unroll
        for (int half = 0; half < 2; ++half) {
            const int hh = g * 2 + half;
            if (hh < 15) {   // prefetch next 2-ks x slab
                const float* nxp = xp + (size_t)(hh + 1) * 64;
#pragma unroll
                for (int i = 0; i < 4; ++i)
                    xn[i] = *reinterpret_cast<const float4*>(nxp + (i >> 1) * 32 + (i & 1) * 4);
            }
#pragma unroll
            for (int kk2 = 0; kk2 < 2; ++kk2) {
                const int kk = half * 2 + kk2;
                const float4 va = xc[kk2 * 2], vb = xc[kk2 * 2 + 1];
                float xf[8] = {va.x, va.y, va.z, va.w, vb.x, vb.y, vb.z, vb.w};
                bf16x8 bh, bl;
#pragma unroll
                for (int j = 0; j < 8; ++j) {
                    float r;
                    bh[j] = bf_hi(xf[j], r);
                    bl[j] = bf_of(xf[j] - r);
                }
                const short* wl = &wlds[buf][kk][0];
                bf16x8 ah0 = *reinterpret_cast<const bf16x8*>(wl +    0 + lane * 8);
                bf16x8 al0 = *reinterpret_cast<const bf16x8*>(wl +  512 + lane * 8);
                bf16x8 ah1 = *reinterpret_cast<const bf16x8*>(wl + 1024 + lane * 8);
                bf16x8 al1 = *reinterpret_cast<const bf16x8*>(wl + 1536 + lane * 8);
                bf16x8 ah2 = *reinterpret_cast<const bf16x8*>(wl + 2048 + lane * 8);
                bf16x8 al2 = *reinterpret_cast<const bf16x8*>(wl + 2560 + lane * 8);
                bf16x8 ah3 = *reinterpret_cast<const bf16x8*>(wl + 3072 + lane * 8);
                bf16x8 al3 = *reinterpret_cast<const bf16x8*>(wl + 3584 + lane * 8);

                acc0 = MFMA16(ah0, bh, acc0);
                acc1 = MFMA16(ah1, bh, acc1);
                acc2 = MFMA16(ah2, bh, acc2);
                acc3 = MFMA16(ah3, bh, acc3);
                acc0 = MFMA16(al0, bh, acc0);
                acc1 = MFMA16(al1, bh, acc1);
                acc2 = MFMA16(al2, bh, acc2);
                acc3 = MFMA16(al3, bh, acc3);
                acc0 = MFMA16(ah0, bl, acc0);
                acc1 = MFMA16(ah1, bl, acc1);
                acc2 = MFMA16(ah2, bl, acc2);
                acc3 = MFMA16(ah3, bl, acc3);
            }
            if (hh < 15) {
#pragma unroll
                for (int i = 0; i < 4; ++i) xc[i] = xn[i];
            }
        }
    }

    const int row0 = split * 64 + (lane >> 4) * 4;
    const int col  = tb + wave * 16 + (lane & 15);
#pragma unroll
    for (int r = 0; r < 4; ++r) {
        htp[(size_t)(row0 +  0 + r) * TOK + col] = acc0[r];
        htp[(size_t)(row0 + 16 + r) * TOK + col] = acc1[r];
        htp[(size_t)(row0 + 32 + r) * TOK + col] = acc2[r];
        htp[(size_t)(row0 + 48 + r) * TOK + col] = acc3[r];
    }
}

// ---------------- K3: MFMA routing (R7-proven); 16 tok/block, 8 waves x 12 tiles
__launch_bounds__(512, 2)
__global__ void k_route2(const float* __restrict__ htp, const float* __restrict__ bias,
                         const short* __restrict__ etfrag, const float* __restrict__ imp,
                         float* __restrict__ part) {
    __shared__ float h_lds[64][16];
    __shared__ float zw[8][2][16];
    __shared__ float coef[4][16];
    __shared__ float impb[16];

    const int tid = threadIdx.x;
    const int w = tid >> 6, lane = tid & 63;
    const int tt = blockIdx.x;
    const int tk = lane & 15, g = lane >> 4;

    // prologue: h = htp[split0] + htp[split1] + bias -> h_lds[64][16]
    if (tid < 256) {
        const int k = tid >> 2, t4 = (tid & 3) << 2;
        const float4* hp4 = reinterpret_cast<const float4*>(htp);
        const int col = tt * 4 + (tid & 3);
        float4 a = hp4[(size_t)k * 4096 + col];
        float4 b = hp4[(size_t)(k + 64) * 4096 + col];
        float bk = bias[k];
        float4 s;
        s.x = a.x + b.x + bk;
        s.y = a.y + b.y + bk;
        s.z = a.z + b.z + bk;
        s.w = a.w + b.w + bk;
        *reinterpret_cast<float4*>(&h_lds[k][t4]) = s;
    }
    if (tid < 16) impb[tid] = imp[tt * 16 + tid];
    __syncthreads();

    // B fragments from h_lds
    bf16x8 bh0, bl0, bh1, bl1;
#pragma unroll
    for (int j = 0; j < 8; ++j) {
        float r;
        float v0 = h_lds[g * 8 + j][tk];
        bh0[j] = bf_hi(v0, r);
        bl0[j] = bf_of(v0 - r);
        float v1 = h_lds[32 + g * 8 + j][tk];
        bh1[j] = bf_hi(v1, r);
        bl1[j] = bf_of(v1 - r);
    }

    const int t0 = w * 12;
    const int sA = sliceOfTile(t0);
    const int sB = sliceOfTile(t0 + 11);
    float zacc0 = 0.f, zacc1 = 0.f;
    float p[12][4];   // fp32 p, statically indexed (full unroll)

    const short* ep = etfrag + (size_t)t0 * 2048 + lane * 16;
#pragma unroll
    for (int ti = 0; ti < 12; ++ti) {
        const short* cp = ep + (size_t)ti * 2048;
        bf16x8 ah0 = *reinterpret_cast<const bf16x8*>(cp);
        bf16x8 al0 = *reinterpret_cast<const bf16x8*>(cp + 8);
        bf16x8 ah1 = *reinterpret_cast<const bf16x8*>(cp + 1024);
        bf16x8 al1 = *reinterpret_cast<const bf16x8*>(cp + 1032);
        f32x4 a0 = {0.f, 0.f, 0.f, 0.f};
        f32x4 a1 = {0.f, 0.f, 0.f, 0.f};
        a0 = MFMA16(ah0, bh0, a0);
        a1 = MFMA16(ah1, bh1, a1);
        a0 = MFMA16(al0, bh0, a0);
        a1 = MFMA16(al1, bh1, a1);
        a0 = MFMA16(ah0, bl0, a0);
        a1 = MFMA16(ah1, bl1, a1);
        const float p0 = __expf(a0[0] + a1[0]);
        const float p1 = __expf(a0[1] + a1[1]);
        const float p2 = __expf(a0[2] + a1[2]);
        const float p3 = __expf(a0[3] + a1[3]);
        p[ti][0] = p0; p[ti][1] = p1; p[ti][2] = p2; p[ti][3] = p3;
        const float zs = (p0 + p1) + (p2 + p3);
        if (sliceOfTile(t0 + ti) == sA) zacc0 += zs; else zacc1 += zs;
    }

    // z: reduce across the 4 row-groups (lanes differing in bits 4,5)
    zacc0 += __shfl_xor(zacc0, 16); zacc0 += __shfl_xor(zacc0, 32);
    zacc1 += __shfl_xor(zacc1, 16); zacc1 += __shfl_xor(zacc1, 32);
    if (lane < 16) { zw[w][0][lane] = zacc0; zw[w][1][lane] = zacc1; }
    __syncthreads();

    if (tid < 64) {
        const int s = tid >> 4, k2 = tid & 15;
        float z = 0.f;
#pragma unroll
        for (int w2 = 0; w2 < 8; ++w2) {
            const int a = sliceOfTile(w2 * 12);
            const int b = sliceOfTile(w2 * 12 + 11);
            if (a == s) z += zw[w2][0][k2];
            if (b == s && b != a) z += zw[w2][1][k2];
        }
        coef[s][k2] = impb[k2] / z;
    }
    __syncthreads();

    // pass 2: dense[n] = sum_t coef[t] * p[t,n]; tokens live across tk lanes
    const float cA = coef[sA][tk];
    const float cB = coef[sB][tk];
    float* pout = part + (size_t)tt * NUSED;
#pragma unroll
    for (int ti = 0; ti < 12; ++ti) {
        const float c = (sliceOfTile(t0 + ti) == sA) ? cA : cB;
        float v0 = p[ti][0] * c, v1 = p[ti][1] * c, v2 = p[ti][2] * c, v3 = p[ti][3] * c;
#pragma unroll
        for (int st = 1; st < 16; st <<= 1) {
            v0 += __shfl_xor(v0, st);
            v1 += __shfl_xor(v1, st);
            v2 += __shfl_xor(v2, st);
            v3 += __shfl_xor(v3, st);
        }
        if (tk == 0)
            *reinterpret_cast<float4*>(&pout[(t0 + ti) * 16 + g * 4]) =
                make_float4(v0, v1, v2, v3);
    }
}

// ---------------- K4a: reduce part 1024 -> 64 rows -------------------------
__launch_bounds__(256)
__global__ void kA(const float* __restrict__ part, float* __restrict__ part2) {
    const int tid = threadIdx.x;
    const int b = blockIdx.x >> 3, g = blockIdx.x & 7;
    const int base = (b * 128 + g * 16) * NUSED;
#pragma unroll
    for (int i = 0; i < 6; ++i) {
        int n = tid + 256 * i;
        float s = 0.f;
#pragma unroll
        for (int r = 0; r < 16; ++r) s += part[base + r * NUSED + n];
        part2[(b * 8 + g) * NUSED + n] = s;
    }
}

// ---------------- K4b: final reduce + top-k sparsify + output --------------
__launch_bounds__(256)
__global__ void kB(const float* __restrict__ part2, float* __restrict__ out) {
    __shared__ float dens[NUSED];
    __shared__ float s_v[4][8];
    __shared__ int   s_n[4][8];
    const int tid = threadIdx.x;
    const int b = blockIdx.x;

#pragma unroll
    for (int i = 0; i < 6; ++i) {
        int n = tid + 256 * i;
        float s = 0.f;
#pragma unroll
        for (int g = 0; g < 8; ++g) s += part2[(b * 8 + g) * NUSED + n];
        dens[n] = s;
    }
    for (int i = tid; i < 1792; i += 256) out[b * 1792 + i] = 0.f;
    __syncthreads();

    const int w = tid >> 6, lane = tid & 63;
    const int soffs[4] = {0, 512, 1024, 1280};
    const int ssz[4]   = {512, 512, 256, 256};
    const int kks[4]   = {8, 8, 4, 6};
    const int ooffs[4] = {0, 512, 1024, 1536};
    const int Sn = ssz[w], soff = soffs[w], kk = kks[w];
    const int nslots = Sn >> 6;

    float v[8];
#pragma unroll
    for (int i = 0; i < 8; ++i)
        v[i] = (i < nslots) ? dens[soff + lane + 64 * i] : -1e30f;

    unsigned rm = 0;
    float ssum = 0.f;
    for (int it = 0; it < kk; ++it) {
        float bv = -1e30f;
        int bn = 0x7fffffff;
#pragma unroll
        for (int i = 0; i < 8; ++i) {
            bool valid = (i < nslots) && !((rm >> i) & 1u);
            if (valid && v[i] > bv) { bv = v[i]; bn = lane + 64 * i; }
        }
#pragma unroll
        for (int off = 32; off; off >>= 1) {
            float ov = __shfl_xor(bv, off);
            int   on = __shfl_xor(bn, off);
            if (ov > bv || (ov == bv && on < bn)) { bv = ov; bn = on; }
        }
        ssum += bv;
        if ((bn & 63) == lane) rm |= 1u << (bn >> 6);
        if (lane == 0) { s_v[w][it] = bv; s_n[w][it] = bn; }
    }
    const float inv = 1.f / (ssum + 1e-8f);
    if (lane < kk) {
        int n = s_n[w][lane];
        float val = s_v[w][lane] * inv;
        out[b * 1792 + ooffs[w] + n] = val;
        if (w == 2) out[b * 1792 + 1280 + n] = val;  // rk = rq
    }
}

extern "C" void kernel_launch(void* const* d_in, const int* in_sizes, int n_in,
                              void* d_out, int out_size, void* d_ws, size_t ws_size,
                              hipStream_t stream) {
    const float* x    = (const float*)d_in[0];
    const float* imp  = (const float*)d_in[1];
    const float* W    = (const float*)d_in[2];
    const float* bias = (const float*)d_in[3];
    const float* emb  = (const float*)d_in[4];
    float* out = (float*)d_out;
    float* ws  = (float*)d_ws;

    short* etfrag = (short*)(ws + WS_ETF);
    float* htp    = ws + WS_HT;
    float* part   = ws + WS_PART;
    float* part2  = ws + WS_PART2;
    short* wfrag  = (short*)(ws + WS_WF);

    k_pre<<<112, 256, 0, stream>>>(emb, W, etfrag, wfrag);
    k_gemm1<<<512, 256, 0, stream>>>(x, wfrag, htp);
    k_route2<<<1024, 512, 0, stream>>>(htp, bias, etfrag, imp, part);
    kA<<<64, 256, 0, stream>>>(part, part2);
    kB<<<8, 256, 0, stream>>>(part2, out);
}